// Round 3
// baseline (9649.606 us; speedup 1.0000x reference)
//
#include <hip/hip_runtime.h>
#include <stdint.h>

#define B_SZ 128
#define SEQL 1024
#define EMB  64
#define HID  512
#define VOC  96

typedef __attribute__((ext_vector_type(8))) short bf16x8;
typedef __attribute__((ext_vector_type(4))) float f32x4;

__device__ __forceinline__ float bf2f(ushort u) {
  union { uint32_t i; float f; } c; c.i = ((uint32_t)u) << 16; return c.f;
}
__device__ __forceinline__ ushort f2bf(float f) {
  union { float f; uint32_t i; } c; c.f = f;
  uint32_t u = c.i;
  return (ushort)((u + 0x7fffu + ((u >> 16) & 1u)) >> 16);
}
__device__ __forceinline__ float fast_tanh(float v) {
  float e = __expf(2.0f * v);
  return (e - 1.0f) * __builtin_amdgcn_rcpf(e + 1.0f);
}

// flags[0]=dtype mode (0 bf16 / 1 f32); flags[1]=x stride (1 int32 / 2 int64)
__global__ void detect_kernel(const ushort* __restrict__ emb_u16,
                              const int* __restrict__ x32, int* __restrict__ flags) {
  if (blockIdx.x != 0 || threadIdx.x != 0) return;
  int wild = 0;
  for (int i = 0; i < 256; ++i) {
    ushort u = emb_u16[i];
    int ex = (u >> 7) & 0xFF;
    if (u != 0 && (ex < 96 || ex > 159)) wild++;
  }
  flags[0] = (wild > 8) ? 1 : 0;
  int allz = 1, anynz = 0;
  for (int i = 0; i < 64; ++i) {
    if (x32[2 * i + 1] != 0) allz = 0;
    if (x32[2 * i] != 0) anynz = 1;
  }
  flags[1] = (allz && anynz) ? 2 : 1;
}

// xh table, packed layout: embwf[v*512 + (h&15)*32 + (h>>4)] = emb[v]@W_xh[:,h] + b_h[h]
template <int MODE>
__global__ void prep_embw(const void* __restrict__ embp, const void* __restrict__ wxhp,
                          const void* __restrict__ bhp, const int* __restrict__ flags,
                          float* __restrict__ embwf) {
  if (flags[0] != MODE) return;
  int gt = blockIdx.x * 256 + threadIdx.x;
  int v = gt >> 9, h = gt & 511;
  float s;
  if (MODE == 0) {
    const ushort* emb = (const ushort*)embp;
    const ushort* wxh = (const ushort*)wxhp;
    s = bf2f(((const ushort*)bhp)[h]);
#pragma unroll 8
    for (int e = 0; e < EMB; ++e) s += bf2f(emb[v * EMB + e]) * bf2f(wxh[e * HID + h]);
  } else {
    const float* emb = (const float*)embp;
    const float* wxh = (const float*)wxhp;
    s = ((const float*)bhp)[h];
#pragma unroll 8
    for (int e = 0; e < EMB; ++e) s += emb[v * EMB + e] * wxh[e * HID + h];
  }
  embwf[(size_t)v * HID + (h & 15) * 32 + (h >> 4)] = s;
}

// B-fragment prep for mfma_f32_16x16x32_bf16, layout [nt][kt][lane][8]
template <int MODE>
__global__ void prep_frag(const void* __restrict__ Wp, const int* __restrict__ flags,
                          ushort* __restrict__ out, int ncols) {
  if (flags[0] != MODE) return;
  int t = blockIdx.x * 256 + threadIdx.x;
  int lane = t & 63, kt = (t >> 6) & 15, nt = t >> 10;
  int n = nt * 16 + (lane & 15);
  int k0 = kt * 32 + (lane >> 4) * 8;
  ushort* o = out + (size_t)t * 8;
  if (MODE == 0) {
    const ushort* W = (const ushort*)Wp;
#pragma unroll
    for (int j = 0; j < 8; ++j) o[j] = W[(size_t)(k0 + j) * ncols + n];
  } else {
    const float* W = (const float*)Wp;
#pragma unroll
    for (int j = 0; j < 8; ++j) o[j] = f2bf(W[(size_t)(k0 + j) * ncols + n]);
  }
}

// W_hh register/LDS split: per wave 8 nt-tiles x 16 kt = 128 frags;
// 93 in VGPR/AGPR, 35 in LDS (140 KB total LDS-W).
#define REG_KT(nt) ((nt) < 5 ? 12 : 11)
#define RIDX(nt, kt) ((nt) < 5 ? (nt) * 12 + (kt) : 60 + ((nt) - 5) * 11 + (kt))
#define LIDX(nt, kt) ((nt) < 5 ? (nt) * 4 + ((kt) - 12) : 20 + ((nt) - 5) * 5 + ((kt) - 11))
#define NFRAG_LDS 35
#define NFRAG_REG 93

// Single-phase fused kernel: 8 blocks, each owns 16 batch rows end-to-end.
// Recurrence (W_hh CU-resident: regs+LDS) with fc GEMM interleaved into the
// K-loop reusing the same A fragments; fc B-frags streamed from L2.
// Zero cross-block communication.
template <int MODE>
__global__ __launch_bounds__(256, 1) void rnn_fused(
    const int* __restrict__ x, const void* __restrict__ hiddenp,
    const float* __restrict__ embwf, const ushort* __restrict__ wf,
    const ushort* __restrict__ fwf, const void* __restrict__ fcbp,
    const int* __restrict__ flags, void* __restrict__ outp) {
  if (flags[0] != MODE) return;
  const int xstr = flags[1];
  // 140 frags * 1 KB = 143360 B + 16 KB h = 159744 B static LDS (cap 163840)
  __shared__ __align__(16) ushort lds_w[140 * 512];
  __shared__ __align__(16) ushort lds_h[16 * 512];  // h in A-frag-linear layout
  const int tid = threadIdx.x;
  const int wid = tid >> 6, lane = tid & 63;
  const int q = lane >> 4, l15 = lane & 15;
  const int rg = blockIdx.x & 7;
  const int rbase = rg * 16;
  // per-thread h-write base (shorts); value (nt,i) at +((nt>>1)*512+(nt&1)*256+i*8)
  const int hwb = wid * 2048 + q * 32 + (l15 >> 3) * 128 + (l15 & 7);
  const size_t BSLV = (size_t)B_SZ * SEQL * VOC;

  // ---- stage W_hh: 93 frags/wave -> regs, 35 -> LDS (fragment-linear, conflict-free)
  const uint4* Wf4 = (const uint4*)wf;
  bf16x8 Wr[NFRAG_REG];
#pragma unroll
  for (int nt = 0; nt < 8; ++nt) {
#pragma unroll
    for (int kt = 0; kt < 16; ++kt) {
      const uint4* s4 = Wf4 + (((size_t)(8 * wid + nt) * 16 + kt) * 64 + lane);
      if (kt < REG_KT(nt)) {
        Wr[RIDX(nt, kt)] = *(const bf16x8*)s4;
      } else {
        *(uint4*)&lds_w[((size_t)wid * NFRAG_LDS + LIDX(nt, kt)) * 512 + lane * 8] = *s4;
      }
    }
  }
  // ---- fc setup: waves own vocab tiles {0,1},{2,3},{4},{5}
  const uint4* Ff4 = (const uint4*)fwf;
  const int ntf0 = (wid < 2) ? 2 * wid : wid + 2;
  const bool two = (wid < 2);
  float b0 = (MODE == 0) ? bf2f(((const ushort*)fcbp)[ntf0 * 16 + l15])
                         : ((const float*)fcbp)[ntf0 * 16 + l15];
  float b1 = two ? ((MODE == 0) ? bf2f(((const ushort*)fcbp)[(ntf0 + 1) * 16 + l15])
                                : ((const float*)fcbp)[(ntf0 + 1) * 16 + l15])
                 : 0.f;
  // ---- stage h_{-1} into lds_h (same mapping as per-step hv writes)
#pragma unroll
  for (int k = 0; k < 32; ++k) {
    int nt = k >> 2, i = k & 3;
    int r = rbase + q * 4 + i, c = (8 * wid + nt) * 16 + l15;
    ushort v = (MODE == 0) ? ((const ushort*)hiddenp)[(size_t)r * HID + c]
                           : f2bf(((const float*)hiddenp)[(size_t)r * HID + c]);
    lds_h[hwb + (nt >> 1) * 512 + (nt & 1) * 256 + i * 8] = v;
  }
  __syncthreads();

  ushort* outb = (ushort*)outp;
  float* outf = (float*)outp;

#pragma unroll 1
  for (int t = 0; t < SEQL; ++t) {
    // x gather (tiny, L2-resident; broadcast within q-groups)
    int xi[4];
#pragma unroll
    for (int i = 0; i < 4; ++i)
      xi[i] = x[((size_t)(rbase + q * 4 + i) * SEQL + t) * xstr];

    f32x4 acc[8];
#pragma unroll
    for (int nt = 0; nt < 8; ++nt) acc[nt] = (f32x4){0.f, 0.f, 0.f, 0.f};
    f32x4 fc0 = {0.f, 0.f, 0.f, 0.f}, fc1 = {0.f, 0.f, 0.f, 0.f};

    // fc B-frag rolling prefetch (5-deep, ~40 regs in flight, L2-resident)
    bf16x8 fb0_[16], fb1_[16];
#pragma unroll
    for (int kp = 0; kp < 5; ++kp) {
      fb0_[kp] = *(const bf16x8*)(Ff4 + ((size_t)(ntf0 * 16 + kp) * 64 + lane));
      if (two) fb1_[kp] = *(const bf16x8*)(Ff4 + ((size_t)((ntf0 + 1) * 16 + kp) * 64 + lane));
    }

    f32x4 er[4][2];
    // K loop: conflict-free b128 A reads (2-deep rotation); W from regs or LDS;
    // fc MFMA interleaved reusing the same A fragment (logits for step t-1).
    bf16x8 ar0 = *(const bf16x8*)&lds_h[0 * 512 + lane * 8];
    bf16x8 ar1 = *(const bf16x8*)&lds_h[1 * 512 + lane * 8];
#pragma unroll
    for (int kt = 0; kt < 16; ++kt) {
      bf16x8 acur = (kt & 1) ? ar1 : ar0;
      if (kt + 2 < 16) {
        bf16x8 nx = *(const bf16x8*)&lds_h[(kt + 2) * 512 + lane * 8];
        if (kt & 1) ar1 = nx; else ar0 = nx;
      }
      if (kt + 5 < 16) {
        fb0_[kt + 5] = *(const bf16x8*)(Ff4 + ((size_t)(ntf0 * 16 + kt + 5) * 64 + lane));
        if (two)
          fb1_[kt + 5] =
              *(const bf16x8*)(Ff4 + ((size_t)((ntf0 + 1) * 16 + kt + 5) * 64 + lane));
      }
      if (kt == 8) {  // xh gather loads: issued mid-loop, consumed at tanh
#pragma unroll
        for (int i = 0; i < 4; ++i) {
          const f32x4* ef = (const f32x4*)(embwf + (size_t)xi[i] * HID + l15 * 32 + wid * 8);
          er[i][0] = ef[0];
          er[i][1] = ef[1];
        }
      }
#pragma unroll
      for (int nt = 0; nt < 8; ++nt) {
        if (kt >= REG_KT(nt)) {
          bf16x8 b = *(const bf16x8*)
              &lds_w[((size_t)wid * NFRAG_LDS + LIDX(nt, kt)) * 512 + lane * 8];
          acc[nt] = __builtin_amdgcn_mfma_f32_16x16x32_bf16(acur, b, acc[nt], 0, 0, 0);
        } else {
          acc[nt] = __builtin_amdgcn_mfma_f32_16x16x32_bf16(acur, Wr[RIDX(nt, kt)],
                                                            acc[nt], 0, 0, 0);
        }
      }
      fc0 = __builtin_amdgcn_mfma_f32_16x16x32_bf16(acur, fb0_[kt], fc0, 0, 0, 0);
      if (two) fc1 = __builtin_amdgcn_mfma_f32_16x16x32_bf16(acur, fb1_[kt], fc1, 0, 0, 0);
    }

    // h_t = tanh(acc + xh)
    ushort hv[32];
#pragma unroll
    for (int nt = 0; nt < 8; ++nt)
#pragma unroll
      for (int i = 0; i < 4; ++i)
        hv[nt * 4 + i] = f2bf(fast_tanh(acc[nt][i] + er[i][nt >> 2][nt & 3]));

    __syncthreads();  // all lds_h reads of h_{t-1} done (empty vm drain: loads consumed)
#pragma unroll
    for (int k = 0; k < 32; ++k) {
      int nt = k >> 2, i = k & 3;
      lds_h[hwb + (nt >> 1) * 512 + (nt & 1) * 256 + i * 8] = hv[k];
    }
    __syncthreads();  // h_t visible

    // logits_{t-1} = h_{t-1} @ fc_w + b: fire-and-forget stores (drain next iter)
    if (t > 0) {
      int tn = t - 1;
#pragma unroll
      for (int i = 0; i < 4; ++i) {
        size_t row = (size_t)(rbase + q * 4 + i) * SEQL + tn;
        float v0 = fc0[i] + b0;
        size_t i0 = row * VOC + ntf0 * 16 + l15;
        if (MODE == 0) outb[i0] = f2bf(v0); else outf[i0] = v0;
        if (two) {
          float v1 = fc1[i] + b1;
          size_t i1 = row * VOC + (ntf0 + 1) * 16 + l15;
          if (MODE == 0) outb[i1] = f2bf(v1); else outf[i1] = v1;
        }
      }
    }
  }

  // ---- epilogue: logits_{1023} from h_{1023} (now in lds_h)
  {
    f32x4 e0 = {0.f, 0.f, 0.f, 0.f}, e1 = {0.f, 0.f, 0.f, 0.f};
#pragma unroll
    for (int kt = 0; kt < 16; ++kt) {
      bf16x8 a = *(const bf16x8*)&lds_h[kt * 512 + lane * 8];
      bf16x8 f0 = *(const bf16x8*)(Ff4 + ((size_t)(ntf0 * 16 + kt) * 64 + lane));
      e0 = __builtin_amdgcn_mfma_f32_16x16x32_bf16(a, f0, e0, 0, 0, 0);
      if (two) {
        bf16x8 f1 = *(const bf16x8*)(Ff4 + ((size_t)((ntf0 + 1) * 16 + kt) * 64 + lane));
        e1 = __builtin_amdgcn_mfma_f32_16x16x32_bf16(a, f1, e1, 0, 0, 0);
      }
    }
#pragma unroll
    for (int i = 0; i < 4; ++i) {
      size_t row = (size_t)(rbase + q * 4 + i) * SEQL + (SEQL - 1);
      float v0 = e0[i] + b0;
      size_t i0 = row * VOC + ntf0 * 16 + l15;
      if (MODE == 0) outb[i0] = f2bf(v0); else outf[i0] = v0;
      if (two) {
        float v1 = e1[i] + b1;
        size_t i1 = row * VOC + (ntf0 + 1) * 16 + l15;
        if (MODE == 0) outb[i1] = f2bf(v1); else outf[i1] = v1;
      }
    }
  }
  // ---- final hidden state to out
  {
    int r = tid >> 4, fk = tid & 15;
    if (MODE == 0) {
      ushort vv[32];
#pragma unroll
      for (int cc = 0; cc < 32; ++cc)
        vv[cc] = lds_h[fk * 512 + (r + ((cc >> 3) & 3) * 16) * 8 + (cc & 7)];
      ushort* o = (ushort*)outp + BSLV + (size_t)(rbase + r) * HID + fk * 32;
#pragma unroll
      for (int m = 0; m < 4; ++m) *(uint4*)(o + m * 8) = *(const uint4*)&vv[m * 8];
    } else {
      float* o = (float*)outp + BSLV + (size_t)(rbase + r) * HID + fk * 32;
#pragma unroll
      for (int cc = 0; cc < 32; ++cc)
        o[cc] = bf2f(lds_h[fk * 512 + (r + ((cc >> 3) & 3) * 16) * 8 + (cc & 7)]);
    }
  }
}

extern "C" void kernel_launch(void* const* d_in, const int* in_sizes, int n_in,
                              void* d_out, int out_size, void* d_ws, size_t ws_size,
                              hipStream_t stream) {
  const void* x      = d_in[0];
  const void* hidden = d_in[1];
  const void* emb    = d_in[2];
  const void* wxh    = d_in[3];
  const void* whh    = d_in[4];
  const void* bh     = d_in[5];
  const void* fcw    = d_in[6];
  const void* fcb    = d_in[7];

  char* ws = (char*)d_ws;
  int*      flags  = (int*)ws;                      // 256 B
  float*    embwf  = (float*)(ws + 256);            // 196608 B (packed f32 xh table)
  ushort*   wfrag  = (ushort*)(ws + 196864);        // 524288 B (W_hh frags)
  ushort*   fwfrag = (ushort*)(ws + 721152);        // 98304 B  (fc_w frags)
  // total 819456 B — below the previously-proven 1.21 MB footprint
  if (ws_size != 0 && ws_size < 819456) return;  // fail visibly, don't fault

  detect_kernel<<<1, 64, 0, stream>>>((const ushort*)emb, (const int*)x, flags);

  prep_embw<0><<<192, 256, 0, stream>>>(emb, wxh, bh, flags, embwf);
  prep_embw<1><<<192, 256, 0, stream>>>(emb, wxh, bh, flags, embwf);
  prep_frag<0><<<128, 256, 0, stream>>>(whh, flags, wfrag, HID);
  prep_frag<1><<<128, 256, 0, stream>>>(whh, flags, wfrag, HID);
  prep_frag<0><<<24, 256, 0, stream>>>(fcw, flags, fwfrag, VOC);
  prep_frag<1><<<24, 256, 0, stream>>>(fcw, flags, fwfrag, VOC);

  rnn_fused<0><<<8, 256, 0, stream>>>((const int*)x, hidden, embwf, wfrag, fwfrag, fcb,
                                      flags, d_out);
  rnn_fused<1><<<8, 256, 0, stream>>>((const int*)x, hidden, embwf, wfrag, fwfrag, fcb,
                                      flags, d_out);
}